// Round 1
// baseline (694.817 us; speedup 1.0000x reference)
//
#include <hip/hip_runtime.h>
#include <stdint.h>

#define H 16
#define HD 64
#define D 1024
#define NTOK 1029
#define BATCH 16
#define NPAD 1152           // 9*128 = 18*64
#define M_ROWS (BATCH*NTOK) // 16464
#define MPAD 16640          // 65*256
#define MT256 65
#define KB 1024
#define PREFIX 5

typedef unsigned short u16;
typedef __attribute__((ext_vector_type(8))) short short8;
typedef __attribute__((ext_vector_type(4))) short short4v;
typedef __attribute__((ext_vector_type(4))) float float4v;
typedef __attribute__((ext_vector_type(4))) unsigned int uint4v;

__device__ __forceinline__ u16 f2bf(float x) {
  unsigned int u = __float_as_uint(x);
  u += 0x7FFFu + ((u >> 16) & 1u);   // RNE
  return (u16)(u >> 16);
}

__device__ __forceinline__ void gload16(const void* g, void* l) {
  __builtin_amdgcn_global_load_lds((const __attribute__((address_space(1))) void*)g,
                                   (__attribute__((address_space(3))) void*)l, 16, 0, 0);
}

// ---------------- fp32 -> bf16 conversion ----------------
__global__ __launch_bounds__(256) void cvt_A_kernel(const float* __restrict__ src,
                                                    u16* __restrict__ dst) {
  int idx = blockIdx.x * 256 + threadIdx.x;  // MPAD*256 threads, 4 elems each
  int m = idx >> 8, k = (idx & 255) * 4;
  float4v x = (float4v)0.f;
  if (m < M_ROWS) x = *(const float4v*)(src + (size_t)m * D + k);
  short4v o;
#pragma unroll
  for (int j = 0; j < 4; j++) o[j] = (short)f2bf(x[j]);
  *(short4v*)(dst + (size_t)m * D + k) = o;
}

__global__ __launch_bounds__(256) void cvt_W_kernel(
    const float* __restrict__ w0, const float* __restrict__ w1,
    const float* __restrict__ w2, const float* __restrict__ w3,
    u16* __restrict__ e0, u16* __restrict__ e1, u16* __restrict__ e2, u16* __restrict__ e3) {
  const float* src = (blockIdx.y == 0) ? w0 : (blockIdx.y == 1) ? w1 : (blockIdx.y == 2) ? w2 : w3;
  u16* dst = (blockIdx.y == 0) ? e0 : (blockIdx.y == 1) ? e1 : (blockIdx.y == 2) ? e2 : e3;
  int idx = blockIdx.x * 256 + threadIdx.x;  // 1024*256 threads
  int m = idx >> 8, k = (idx & 255) * 4;
  float4v x = *(const float4v*)(src + (size_t)m * D + k);
  short4v o;
#pragma unroll
  for (int j = 0; j < 4; j++) o[j] = (short)f2bf(x[j]);
  *(short4v*)(dst + (size_t)m * D + k) = o;
}

// ---------------- 256x256 bf16 GEMM, 8-phase counted-vmcnt schedule ----------------
// LDS tiles: [256 rows][64 k] bf16 per operand, double-buffered (128 KiB total).
// Swizzle (involution, both-sides): 16B-slot within a 128B row: slot ^= (row&7).
//   - global_load_lds dest stays LINEAR (HW writes base+lane*16); the SOURCE global
//     address carries the inverse permutation (same involution).
//   - ds_read applies the same XOR -> lanes ar=0..7 hit 8 distinct slots (was 16-way
//     same-bank at 128B row stride).
// Prefetch: K-tile t+2 burst-issued after all waves finish reading buf[t&1];
// s_waitcnt vmcnt(8) keeps those 8 loads in flight across the barrier (never 0
// until the last two tiles).

__device__ __forceinline__ void stage256(const u16* __restrict__ gA, const u16* __restrict__ gB,
                                         u16* dA, u16* dB, int dwo) {
#pragma unroll
  for (int i = 0; i < 4; i++)
    gload16(gA + (size_t)i * 64 * KB, dA + i * 4096 + dwo);
#pragma unroll
  for (int i = 0; i < 4; i++)
    gload16(gB + (size_t)i * 64 * KB, dB + i * 4096 + dwo);
}

#define GPHASE(mh, soffv, loadB)                                                          \
  {                                                                                       \
    short8 afr[4];                                                                        \
    _Pragma("unroll") for (int m4 = 0; m4 < 4; m4++)                                      \
        afr[m4] = *(const short8*)(pA + (wm_idx * 128 + ((mh)*4 + m4) * 16 + ar) * 64 + (soffv)); \
    if (loadB) {                                                                          \
      _Pragma("unroll") for (int ns = 0; ns < 4; ns++)                                    \
          bfr[ns] = *(const short8*)(pB + (wn_idx * 64 + ns * 16 + ar) * 64 + (soffv));   \
    }                                                                                     \
    __builtin_amdgcn_s_barrier();                                                         \
    asm volatile("s_waitcnt lgkmcnt(0)" ::: "memory");                                    \
    __builtin_amdgcn_s_setprio(1);                                                        \
    _Pragma("unroll") for (int m4 = 0; m4 < 4; m4++) {                                    \
      _Pragma("unroll") for (int ns = 0; ns < 4; ns++)                                    \
        acc[(mh)*4 + m4][ns] = __builtin_amdgcn_mfma_f32_16x16x32_bf16(                   \
            afr[m4], bfr[ns], acc[(mh)*4 + m4][ns], 0, 0, 0);                             \
    }                                                                                     \
    __builtin_amdgcn_s_setprio(0);                                                        \
    __builtin_amdgcn_s_barrier();                                                         \
  }

__device__ __forceinline__ void gemm256_mainloop(const u16* __restrict__ A,
                                                 const u16* __restrict__ Bw,
                                                 u16 As[2][16384], u16 Bs[2][16384],
                                                 int mtile, int ntile, float4v acc[8][4]) {
  const int tid = threadIdx.x;
  const int lane = tid & 63;
  const int wave = tid >> 6;
  const int wm_idx = wave >> 2;   // 0..1
  const int wn_idx = wave & 3;    // 0..3
  const int ar = lane & 15;
  const int kq = lane >> 4;
  // swizzled 16B-slot offsets (u16 units) for k-slice 0 / 1: slot = ks*4+kq, ^ (row&7)=(ar&7)
  const int s0 = ((kq)     ^ (ar & 7)) * 8;
  const int s1 = ((4 + kq) ^ (ar & 7)) * 8;
  // staging: thread covers 16B chunk (i*512+tid); row=(i*64 + tid>>3), lds slot=tid&7,
  // source slot = (tid&7) ^ (row&7)
  const int srow = tid >> 3;
  const int scol = ((tid & 7) ^ (srow & 7)) * 8;
  const int dwo = (tid & ~63) * 8;  // wave-uniform LDS dest base (u16 units)
  const size_t abase = (size_t)mtile * 256 * KB + (size_t)srow * KB + scol;
  const size_t bbase = (size_t)ntile * 256 * KB + (size_t)srow * KB + scol;

#pragma unroll
  for (int i = 0; i < 8; i++)
#pragma unroll
    for (int j = 0; j < 4; j++) acc[i][j] = (float4v)0.f;

  // prologue: stage K-tiles 0 and 1, wait tile0 only (tile1 stays in flight)
  stage256(A + abase, Bw + bbase, As[0], Bs[0], dwo);
  stage256(A + abase + 64, Bw + bbase + 64, As[1], Bs[1], dwo);
  asm volatile("s_waitcnt vmcnt(8)" ::: "memory");
  __builtin_amdgcn_s_barrier();

  short8 bfr[4];
  for (int t = 0; t < 16; ++t) {
    const u16* pA = As[t & 1];
    const u16* pB = Bs[t & 1];
    GPHASE(0, s0, 1)
    GPHASE(1, s0, 0)
    GPHASE(0, s1, 1)
    GPHASE(1, s1, 0)
    // last phase's trailing barrier == all waves done reading buf[t&1]; safe to restage
    if (t < 14) {
      const int k0 = (t + 2) * 64;
      stage256(A + abase + k0, Bw + bbase + k0, As[t & 1], Bs[t & 1], dwo);
      asm volatile("s_waitcnt vmcnt(8)" ::: "memory");  // tile t+1 done, t+2 in flight
    } else {
      asm volatile("s_waitcnt vmcnt(0)" ::: "memory");  // epilogue tiles: drain
    }
    __builtin_amdgcn_s_barrier();
  }
}

// ---------------- QKV projection + bias + RoPE ----------------
// q/k in [bh][n][64]; v transposed: vt[bh][d][n] (n padded to NPAD).
__global__ __launch_bounds__(512, 2) void gemm_qkv_kernel(
    const u16* __restrict__ A,
    const u16* __restrict__ Wqb, const u16* __restrict__ Wkb, const u16* __restrict__ Wvb,
    const float* __restrict__ bq, const float* __restrict__ bk, const float* __restrict__ bv,
    const float* __restrict__ sinp, const float* __restrict__ cosp,
    u16* __restrict__ qb, u16* __restrict__ kb, u16* __restrict__ vt) {
  __shared__ __align__(16) u16 As[2][16384];
  __shared__ __align__(16) u16 Bs[2][16384];
  const int z = blockIdx.z;
  const u16* Bw = (z == 0) ? Wqb : (z == 1) ? Wkb : Wvb;
  const float* bias = (z == 0) ? bq : (z == 1) ? bk : bv;
  const int ntile = blockIdx.x, mtile = blockIdx.y;
  float4v acc[8][4];
  gemm256_mainloop(A, Bw, As, Bs, mtile, ntile, acc);

  const int tid = threadIdx.x, lane = tid & 63, wave = tid >> 6;
  const int wm_idx = wave >> 2, wn_idx = wave & 3;
  const int ar = lane & 15, kq = lane >> 4;
  const int rowb = mtile * 256 + wm_idx * 128;
  const int colb = ntile * 256 + wn_idx * 64;
#pragma unroll
  for (int ms = 0; ms < 8; ms++) {
#pragma unroll
    for (int r = 0; r < 4; r++) {
      int grow = rowb + ms * 16 + kq * 4 + r;
      if (grow >= M_ROWS) continue;
      int b = grow / NTOK;
      int n = grow - b * NTOK;
      bool dorope = (z != 2) && (n >= PREFIX);
      int pos = n - PREFIX;
#pragma unroll
      for (int ns = 0; ns < 4; ns++) {
        int col = colb + ns * 16 + ar;
        int hh = col >> 6, d = col & 63;
        float y = acc[ms][ns][r] + bias[col];
        if (z == 2) {
          vt[((size_t)(b * H + hh) * 64 + d) * NPAD + n] = f2bf(y);
          continue;
        }
        if (dorope) {
          float xp = acc[ms][ns ^ 2][r] + bias[col ^ 32];  // partner d^32, same lane
          float c = cosp[pos * HD + d], s = sinp[pos * HD + d];
          y = y * c + ((d < 32) ? -xp : xp) * s;
        }
        if (z == 0) y *= 0.125f;  // fold 1/sqrt(HD) into q
        u16* outp = (z == 0) ? qb : kb;
        outp[((size_t)(b * H + hh) * NPAD + n) * 64 + d] = f2bf(y);
      }
    }
  }
}

// ---------------- flash attention: 128 q-rows/block, 4 waves x 32 rows ----------------
// Fixed-shift softmax (scores hard-bounded; shift cancels in normalization).
#define SSHIFT 3.0f
#define NJT 17   // ceil(NTOK/64): j-tiles 0..16; tile 16 masked, NO tile beyond
__global__ __launch_bounds__(256) void attn_kernel(const u16* __restrict__ qb,
                                                   const u16* __restrict__ kb,
                                                   const u16* __restrict__ vt,
                                                   u16* __restrict__ ao) {
  __shared__ __align__(16) u16 sQ[128 * 72];  // 18KB; per-wave sP (32x72) overlays own rows after preload
  __shared__ __align__(16) u16 sK[64 * 72];   // rows = j, cols = d
  __shared__ __align__(16) u16 sV[64 * 72];   // rows = d, cols = j (V^T staged directly)
  const int tid = threadIdx.x, lane = tid & 63, wave = tid >> 6;
  const int ar = lane & 15, kq = lane >> 4;
  const int qt = blockIdx.x, hh = blockIdx.y, b = blockIdx.z;
  const int bh = b * H + hh;
  const u16* qbase = qb + (size_t)bh * NPAD * 64;
  const u16* kbase = kb + (size_t)bh * NPAD * 64;
  const u16* vbase = vt + (size_t)bh * 64 * NPAD;

  // stage Q tile (128 x 64, stride 72)
#pragma unroll
  for (int i = 0; i < 4; i++) {
    int chunk = i * 256 + tid;
    int row = chunk >> 3, c = chunk & 7;
    *(uint4v*)(sQ + row * 72 + c * 8) =
        *(const uint4v*)(qbase + (size_t)(qt * 128 + row) * 64 + c * 8);
  }
  __syncthreads();
  short8 aq[2][2];  // this wave's q A-frags (rows wave*32 + ms*16 + ar)
#pragma unroll
  for (int ms = 0; ms < 2; ms++)
#pragma unroll
    for (int ki = 0; ki < 2; ki++)
      aq[ms][ki] = *(const short8*)(sQ + (wave * 32 + ms * 16 + ar) * 72 + ki * 32 + kq * 8);
  u16* sP = sQ + wave * 32 * 72;  // wave-private P tile (32 x 64) over this wave's own sQ rows

  float rs[2][4];
  float4v o_acc[2][4];
#pragma unroll
  for (int ms = 0; ms < 2; ms++)
#pragma unroll
    for (int r = 0; r < 4; r++) rs[ms][r] = 0.f;
#pragma unroll
  for (int ms = 0; ms < 2; ms++)
#pragma unroll
    for (int t = 0; t < 4; t++) o_acc[ms][t] = (float4v)0.f;

  for (int jt = 0; jt < NJT; jt++) {
    __syncthreads();  // prev-iteration sK/sV frag reads complete
#pragma unroll
    for (int i = 0; i < 2; i++) {
      int chunk = i * 256 + tid;
      int row = chunk >> 3, c = chunk & 7;
      *(uint4v*)(sK + row * 72 + c * 8) =
          *(const uint4v*)(kbase + (size_t)(jt * 64 + row) * 64 + c * 8);
      *(uint4v*)(sV + row * 72 + c * 8) =
          *(const uint4v*)(vbase + (size_t)row * NPAD + jt * 64 + c * 8);
    }
    __syncthreads();

    // S = q . k  (2 x 16 rows x 64 j)
    float4v s[2][4];
#pragma unroll
    for (int ms = 0; ms < 2; ms++)
#pragma unroll
      for (int t = 0; t < 4; t++) s[ms][t] = (float4v)0.f;
#pragma unroll
    for (int ki = 0; ki < 2; ki++) {
#pragma unroll
      for (int t = 0; t < 4; t++) {
        short8 bk8 = *(const short8*)(sK + (t * 16 + ar) * 72 + ki * 32 + kq * 8);
#pragma unroll
        for (int ms = 0; ms < 2; ms++)
          s[ms][t] = __builtin_amdgcn_mfma_f32_16x16x32_bf16(aq[ms][ki], bk8, s[ms][t], 0, 0, 0);
      }
    }
    // mask j >= NTOK (only the last tile has any)
    if (jt == NJT - 1) {
#pragma unroll
      for (int t = 0; t < 4; t++)
        if ((NJT - 1) * 64 + t * 16 + ar >= NTOK) {
#pragma unroll
          for (int ms = 0; ms < 2; ms++) s[ms][t] = (float4v)(-INFINITY);
        }
    }
    // p = exp(s - SSHIFT); accumulate per-lane row partial sums; stage P
    asm volatile("" ::: "memory");
#pragma unroll
    for (int ms = 0; ms < 2; ms++)
#pragma unroll
      for (int t = 0; t < 4; t++)
#pragma unroll
        for (int r = 0; r < 4; r++) {
          float p = __expf(s[ms][t][r] - SSHIFT);
          rs[ms][r] += p;
          sP[(ms * 16 + kq * 4 + r) * 72 + t * 16 + ar] = f2bf(p);
        }
    asm volatile("" ::: "memory");  // LDS is per-wave in-order; just stop compiler reordering
#pragma unroll
    for (int ki = 0; ki < 2; ki++) {
#pragma unroll
      for (int ms = 0; ms < 2; ms++) {
        short8 ap = *(const short8*)(sP + (ms * 16 + ar) * 72 + ki * 32 + kq * 8);
#pragma unroll
        for (int t = 0; t < 4; t++) {
          short8 bv8 = *(const short8*)(sV + (t * 16 + ar) * 72 + ki * 32 + kq * 8);
          o_acc[ms][t] = __builtin_amdgcn_mfma_f32_16x16x32_bf16(ap, bv8, o_acc[ms][t], 0, 0, 0);
        }
      }
    }
  }
  // epilogue: one row-sum reduce, normalize, write attn_out bf16 for the O-GEMM
#pragma unroll
  for (int ms = 0; ms < 2; ms++)
#pragma unroll
    for (int r = 0; r < 4; r++) {
      float l = rs[ms][r];
#pragma unroll
      for (int off = 1; off < 16; off <<= 1) l += __shfl_xor(l, off, 64);
      int i = qt * 128 + wave * 32 + ms * 16 + kq * 4 + r;
      if (i >= NTOK) continue;
      float inv = 1.f / l;
      size_t mg = (size_t)b * NTOK + i;
#pragma unroll
      for (int t = 0; t < 4; t++)
        ao[mg * D + hh * 64 + t * 16 + ar] = f2bf(o_acc[ms][t][r] * inv);
    }
}

// ---------------- output projection ----------------
__global__ __launch_bounds__(512, 2) void gemm_o_kernel(const u16* __restrict__ A,
                                                        const u16* __restrict__ Wob,
                                                        const float* __restrict__ bo,
                                                        float* __restrict__ out) {
  __shared__ __align__(16) u16 As[2][16384];
  __shared__ __align__(16) u16 Bs[2][16384];
  const int ntile = blockIdx.x, mtile = blockIdx.y;
  float4v acc[8][4];
  gemm256_mainloop(A, Wob, As, Bs, mtile, ntile, acc);
  const int tid = threadIdx.x, lane = tid & 63, wave = tid >> 6;
  const int wm_idx = wave >> 2, wn_idx = wave & 3;
  const int ar = lane & 15, kq = lane >> 4;
  const int rowb = mtile * 256 + wm_idx * 128;
  const int colb = ntile * 256 + wn_idx * 64;
#pragma unroll
  for (int ms = 0; ms < 8; ms++) {
#pragma unroll
    for (int r = 0; r < 4; r++) {
      int grow = rowb + ms * 16 + kq * 4 + r;
      if (grow >= M_ROWS) continue;
#pragma unroll
      for (int ns = 0; ns < 4; ns++) {
        int col = colb + ns * 16 + ar;
        out[(size_t)grow * D + col] = acc[ms][ns][r] + bo[col];
      }
    }
  }
}

extern "C" void kernel_launch(void* const* d_in, const int* in_sizes, int n_in,
                              void* d_out, int out_size, void* d_ws, size_t ws_size,
                              hipStream_t stream) {
  const float* hidden = (const float*)d_in[0];
  const float* sinp = (const float*)d_in[1];
  const float* cosp = (const float*)d_in[2];
  const float* Wq = (const float*)d_in[3]; const float* bq = (const float*)d_in[4];
  const float* Wk = (const float*)d_in[5]; const float* bk = (const float*)d_in[6];
  const float* Wv = (const float*)d_in[7]; const float* bv = (const float*)d_in[8];
  const float* Wo = (const float*)d_in[9]; const float* bo = (const float*)d_in[10];
  float* out = (float*)d_out;
  (void)in_sizes; (void)n_in; (void)out_size; (void)ws_size;

  char* ws = (char*)d_ws;
  size_t off = 0;
  auto carve = [&](size_t elems) {
    u16* p = (u16*)(ws + off);
    off += ((elems * 2 + 255) & ~(size_t)255);
    return p;
  };
  u16* A_bf = carve((size_t)MPAD * KB);             // 34.1 MB (reused for attn_out)
  u16* Wqb = carve((size_t)D * KB);                 // 2.1 MB x4
  u16* Wkb = carve((size_t)D * KB);
  u16* Wvb = carve((size_t)D * KB);
  u16* Wob = carve((size_t)D * KB);
  u16* q_b = carve((size_t)BATCH * H * NPAD * 64);  // 37.7 MB x3   (total ~156 MB)
  u16* k_b = carve((size_t)BATCH * H * NPAD * 64);
  u16* v_t = carve((size_t)BATCH * H * NPAD * 64);

  hipLaunchKernelGGL(cvt_A_kernel, dim3(MPAD), dim3(256), 0, stream, hidden, A_bf);
  hipLaunchKernelGGL(cvt_W_kernel, dim3(1024, 4), dim3(256), 0, stream,
                     Wq, Wk, Wv, Wo, Wqb, Wkb, Wvb, Wob);
  hipLaunchKernelGGL(gemm_qkv_kernel, dim3(4, MT256, 3), dim3(512), 0, stream,
                     A_bf, Wqb, Wkb, Wvb, bq, bk, bv, sinp, cosp, q_b, k_b, v_t);
  hipLaunchKernelGGL(attn_kernel, dim3(9, H, BATCH), dim3(256), 0, stream, q_b, k_b, v_t, A_bf);
  hipLaunchKernelGGL(gemm_o_kernel, dim3(4, MT256), dim3(512), 0, stream, A_bf, Wob, bo, out);
}

// Round 3
// 655.480 us; speedup vs baseline: 1.0600x; 1.0600x over previous
//
#include <hip/hip_runtime.h>
#include <stdint.h>

#define H 16
#define HD 64
#define D 1024
#define NTOK 1029
#define BATCH 16
#define NPAD 1152           // 9*128 = 18*64
#define M_ROWS (BATCH*NTOK) // 16464
#define MPAD 16640          // 65*256
#define MT256 65
#define KB 1024
#define PREFIX 5

typedef unsigned short u16;
typedef __attribute__((ext_vector_type(8))) short short8;
typedef __attribute__((ext_vector_type(4))) short short4v;
typedef __attribute__((ext_vector_type(4))) float float4v;
typedef __attribute__((ext_vector_type(4))) unsigned int uint4v;

__device__ __forceinline__ u16 f2bf(float x) {
  unsigned int u = __float_as_uint(x);
  u += 0x7FFFu + ((u >> 16) & 1u);   // RNE
  return (u16)(u >> 16);
}

__device__ __forceinline__ void gload16(const void* g, void* l) {
  __builtin_amdgcn_global_load_lds((const __attribute__((address_space(1))) void*)g,
                                   (__attribute__((address_space(3))) void*)l, 16, 0, 0);
}

// ---------------- fp32 -> bf16 conversion ----------------
__global__ __launch_bounds__(256) void cvt_A_kernel(const float* __restrict__ src,
                                                    u16* __restrict__ dst) {
  int idx = blockIdx.x * 256 + threadIdx.x;  // MPAD*256 threads, 4 elems each
  int m = idx >> 8, k = (idx & 255) * 4;
  float4v x = (float4v)0.f;
  if (m < M_ROWS) x = *(const float4v*)(src + (size_t)m * D + k);
  short4v o;
#pragma unroll
  for (int j = 0; j < 4; j++) o[j] = (short)f2bf(x[j]);
  *(short4v*)(dst + (size_t)m * D + k) = o;
}

__global__ __launch_bounds__(256) void cvt_W_kernel(
    const float* __restrict__ w0, const float* __restrict__ w1,
    const float* __restrict__ w2, const float* __restrict__ w3,
    u16* __restrict__ e0, u16* __restrict__ e1, u16* __restrict__ e2, u16* __restrict__ e3) {
  const float* src = (blockIdx.y == 0) ? w0 : (blockIdx.y == 1) ? w1 : (blockIdx.y == 2) ? w2 : w3;
  u16* dst = (blockIdx.y == 0) ? e0 : (blockIdx.y == 1) ? e1 : (blockIdx.y == 2) ? e2 : e3;
  int idx = blockIdx.x * 256 + threadIdx.x;  // 1024*256 threads
  int m = idx >> 8, k = (idx & 255) * 4;
  float4v x = *(const float4v*)(src + (size_t)m * D + k);
  short4v o;
#pragma unroll
  for (int j = 0; j < 4; j++) o[j] = (short)f2bf(x[j]);
  *(short4v*)(dst + (size_t)m * D + k) = o;
}

// ---------------- 256x256 bf16 GEMM, 8-phase counted-vmcnt schedule ----------------
// Four DISTINCT __shared__ arrays (As0/Bs0 = even K-tiles, As1/Bs1 = odd) so the
// compiler's LDS-DMA alias tracking can PROVE each ds_read never aliases an
// outstanding global_load_lds (the <=2-load residue after each boundary vmcnt(2)
// always targets the OTHER buffer) -> no injected vmcnt(0) drains.
// Staging is per-phase (1 half-tile = 2 gload16/thread/phase), m201-style:
//   tile T phases 1-3 stage T+1.{A1,B0,B1} into the other buffer;
//   at the boundary (post trailing barrier, current buffer fully read) stage
//   T+2.A0 into the current buffer, then s_waitcnt vmcnt(2): T+1 landed,
//   T+2.A0 stays in flight. Never drains to 0 until tile 14.
// Swizzle (involution, both sides): 16B slot within a 128B row ^= (row&7);
// global_load_lds dest stays linear, SOURCE carries the inverse permutation.

#define STG(dst, src)                          \
  do {                                         \
    gload16((src), (dst) + dswo);              \
    gload16((src) + 64 * KB, (dst) + 4096 + dswo); \
  } while (0)

#define GPHASE(mh, soffv, loadB, pA, pB, ...)                                             \
  {                                                                                       \
    short8 afr[4];                                                                        \
    _Pragma("unroll") for (int m4 = 0; m4 < 4; m4++)                                      \
        afr[m4] = *(const short8*)((pA) + (wm_idx * 128 + ((mh)*4 + m4) * 16 + ar) * 64 + (soffv)); \
    if (loadB) {                                                                          \
      _Pragma("unroll") for (int ns = 0; ns < 4; ns++)                                    \
          bfr[ns] = *(const short8*)((pB) + (wn_idx * 64 + ns * 16 + ar) * 64 + (soffv)); \
    }                                                                                     \
    __VA_ARGS__                                                                           \
    __builtin_amdgcn_s_barrier();                                                         \
    asm volatile("s_waitcnt lgkmcnt(0)" ::: "memory");                                    \
    __builtin_amdgcn_s_setprio(1);                                                        \
    _Pragma("unroll") for (int m4 = 0; m4 < 4; m4++) {                                    \
      _Pragma("unroll") for (int ns = 0; ns < 4; ns++)                                    \
        acc[(mh)*4 + m4][ns] = __builtin_amdgcn_mfma_f32_16x16x32_bf16(                   \
            afr[m4], bfr[ns], acc[(mh)*4 + m4][ns], 0, 0, 0);                             \
    }                                                                                     \
    __builtin_amdgcn_s_setprio(0);                                                        \
    __builtin_amdgcn_s_barrier();                                                         \
  }

// One K-tile: 4 quadrant phases + boundary restage/wait.
// pA/pB: buffer holding THIS tile. oA/oB: other buffer (tile n1 = T+1 lands there).
// S1: stage T+1 halves during phases. S2: stage T+2.A0 (tile n2) + counted wait.
#define TILE(pA, pB, oA, oB, n1, S1, n2, S2)                                         \
  GPHASE(0, s0, 1, pA, pB, if (S1) STG((oA) + 8192, Ab + 128 * KB + (size_t)(n1) * 64);) \
  GPHASE(1, s0, 0, pA, pB, if (S1) STG((oB), Bb + (size_t)(n1) * 64);)               \
  GPHASE(0, s1, 1, pA, pB, if (S1) STG((oB) + 8192, Bb + 128 * KB + (size_t)(n1) * 64);) \
  GPHASE(1, s1, 0, pA, pB, )                                                         \
  if (S2) {                                                                          \
    STG((pA), Ab + (size_t)(n2) * 64);                                               \
    asm volatile("s_waitcnt vmcnt(2)" ::: "memory");                                 \
  } else {                                                                           \
    asm volatile("s_waitcnt vmcnt(0)" ::: "memory");                                 \
  }                                                                                  \
  __builtin_amdgcn_s_barrier();

__device__ __forceinline__ void gemm256_mainloop(const u16* __restrict__ A,
                                                 const u16* __restrict__ Bw,
                                                 u16* As0, u16* Bs0, u16* As1, u16* Bs1,
                                                 int mtile, int ntile, float4v acc[8][4]) {
  const int tid = threadIdx.x;
  const int lane = tid & 63;
  const int wave = tid >> 6;
  const int wm_idx = wave >> 2;   // 0..1
  const int wn_idx = wave & 3;    // 0..3
  const int ar = lane & 15;
  const int kq = lane >> 4;
  // swizzled 16B-slot offsets (u16 units) for k-slice 0/1: slot = ks*4+kq, ^ (row&7)=(ar&7)
  const int s0 = ((kq)     ^ (ar & 7)) * 8;
  const int s1 = ((4 + kq) ^ (ar & 7)) * 8;
  // staging: thread covers rows srow, srow+64 of each 128-row half; source slot pre-swizzled
  const int srow = tid >> 3;                       // 0..63
  const int scol = ((tid & 7) ^ (srow & 7)) * 8;   // u16 units
  const int dswo = (tid & ~63) * 8;                // wave-uniform LDS dest base (u16)
  const u16* Ab = A + (size_t)mtile * 256 * KB + (size_t)srow * KB + scol;
  const u16* Bb = Bw + (size_t)ntile * 256 * KB + (size_t)srow * KB + scol;

#pragma unroll
  for (int i = 0; i < 8; i++)
#pragma unroll
    for (int j = 0; j < 4; j++) acc[i][j] = (float4v)0.f;

  // prologue: tile0 fully + tile1.A0; wait tile0 (tile1.A0 stays in flight)
  STG(As0, Ab);
  STG(As0 + 8192, Ab + 128 * KB);
  STG(Bs0, Bb);
  STG(Bs0 + 8192, Bb + 128 * KB);
  STG(As1, Ab + 64);
  asm volatile("s_waitcnt vmcnt(2)" ::: "memory");
  __builtin_amdgcn_s_barrier();

  short8 bfr[4];
#pragma unroll 1
  for (int t2 = 0; t2 < 14; t2 += 2) {
    TILE(As0, Bs0, As1, Bs1, t2 + 1, 1, t2 + 2, 1)   // even tile
    TILE(As1, Bs1, As0, Bs0, t2 + 2, 1, t2 + 3, 1)   // odd tile
  }
  TILE(As0, Bs0, As1, Bs1, 15, 1, 0, 0)   // tile 14: stage T15.{A1,B0,B1}; drain
  TILE(As1, Bs1, As0, Bs0, 0, 0, 0, 0)    // tile 15: no staging
}

// ---------------- QKV projection + bias + RoPE ----------------
// q/k in [bh][n][64]; v transposed: vt[bh][d][n] (n padded to NPAD).
__global__ __launch_bounds__(512, 2) void gemm_qkv_kernel(
    const u16* __restrict__ A,
    const u16* __restrict__ Wqb, const u16* __restrict__ Wkb, const u16* __restrict__ Wvb,
    const float* __restrict__ bq, const float* __restrict__ bk, const float* __restrict__ bv,
    const float* __restrict__ sinp, const float* __restrict__ cosp,
    u16* __restrict__ qb, u16* __restrict__ kb, u16* __restrict__ vt) {
  __shared__ __align__(16) u16 As0[16384];
  __shared__ __align__(16) u16 Bs0[16384];
  __shared__ __align__(16) u16 As1[16384];
  __shared__ __align__(16) u16 Bs1[16384];
  const int z = blockIdx.z;
  const u16* Bw = (z == 0) ? Wqb : (z == 1) ? Wkb : Wvb;
  const float* bias = (z == 0) ? bq : (z == 1) ? bk : bv;
  const int ntile = blockIdx.x, mtile = blockIdx.y;
  float4v acc[8][4];
  gemm256_mainloop(A, Bw, As0, Bs0, As1, Bs1, mtile, ntile, acc);

  const int tid = threadIdx.x, lane = tid & 63, wave = tid >> 6;
  const int wm_idx = wave >> 2, wn_idx = wave & 3;
  const int ar = lane & 15, kq = lane >> 4;
  const int rowb = mtile * 256 + wm_idx * 128;
  const int colb = ntile * 256 + wn_idx * 64;
#pragma unroll
  for (int ms = 0; ms < 8; ms++) {
#pragma unroll
    for (int r = 0; r < 4; r++) {
      int grow = rowb + ms * 16 + kq * 4 + r;
      if (grow >= M_ROWS) continue;
      int b = grow / NTOK;
      int n = grow - b * NTOK;
      bool dorope = (z != 2) && (n >= PREFIX);
      int pos = n - PREFIX;
#pragma unroll
      for (int ns = 0; ns < 4; ns++) {
        int col = colb + ns * 16 + ar;
        int hh = col >> 6, d = col & 63;
        float y = acc[ms][ns][r] + bias[col];
        if (z == 2) {
          vt[((size_t)(b * H + hh) * 64 + d) * NPAD + n] = f2bf(y);
          continue;
        }
        if (dorope) {
          float xp = acc[ms][ns ^ 2][r] + bias[col ^ 32];  // partner d^32, same lane
          float c = cosp[pos * HD + d], s = sinp[pos * HD + d];
          y = y * c + ((d < 32) ? -xp : xp) * s;
        }
        if (z == 0) y *= 0.125f;  // fold 1/sqrt(HD) into q
        u16* outp = (z == 0) ? qb : kb;
        outp[((size_t)(b * H + hh) * NPAD + n) * 64 + d] = f2bf(y);
      }
    }
  }
}

// ---------------- flash attention: 128 q-rows/block, 4 waves x 32 rows ----------------
// Fixed-shift softmax (scores hard-bounded; shift cancels in normalization).
#define SSHIFT 3.0f
#define NJT 17   // ceil(NTOK/64): j-tiles 0..16; tile 16 masked, NO tile beyond
__global__ __launch_bounds__(256) void attn_kernel(const u16* __restrict__ qb,
                                                   const u16* __restrict__ kb,
                                                   const u16* __restrict__ vt,
                                                   u16* __restrict__ ao) {
  __shared__ __align__(16) u16 sQ[128 * 72];  // 18KB; per-wave sP (32x72) overlays own rows after preload
  __shared__ __align__(16) u16 sK[64 * 72];   // rows = j, cols = d
  __shared__ __align__(16) u16 sV[64 * 72];   // rows = d, cols = j (V^T staged directly)
  const int tid = threadIdx.x, lane = tid & 63, wave = tid >> 6;
  const int ar = lane & 15, kq = lane >> 4;
  const int qt = blockIdx.x, hh = blockIdx.y, b = blockIdx.z;
  const int bh = b * H + hh;
  const u16* qbase = qb + (size_t)bh * NPAD * 64;
  const u16* kbase = kb + (size_t)bh * NPAD * 64;
  const u16* vbase = vt + (size_t)bh * 64 * NPAD;

  // stage Q tile (128 x 64, stride 72)
#pragma unroll
  for (int i = 0; i < 4; i++) {
    int chunk = i * 256 + tid;
    int row = chunk >> 3, c = chunk & 7;
    *(uint4v*)(sQ + row * 72 + c * 8) =
        *(const uint4v*)(qbase + (size_t)(qt * 128 + row) * 64 + c * 8);
  }
  __syncthreads();
  short8 aq[2][2];  // this wave's q A-frags (rows wave*32 + ms*16 + ar)
#pragma unroll
  for (int ms = 0; ms < 2; ms++)
#pragma unroll
    for (int ki = 0; ki < 2; ki++)
      aq[ms][ki] = *(const short8*)(sQ + (wave * 32 + ms * 16 + ar) * 72 + ki * 32 + kq * 8);
  u16* sP = sQ + wave * 32 * 72;  // wave-private P tile (32 x 64) over this wave's own sQ rows

  float rs[2][4];
  float4v o_acc[2][4];
#pragma unroll
  for (int ms = 0; ms < 2; ms++)
#pragma unroll
    for (int r = 0; r < 4; r++) rs[ms][r] = 0.f;
#pragma unroll
  for (int ms = 0; ms < 2; ms++)
#pragma unroll
    for (int t = 0; t < 4; t++) o_acc[ms][t] = (float4v)0.f;

  for (int jt = 0; jt < NJT; jt++) {
    __syncthreads();  // prev-iteration sK/sV frag reads complete
#pragma unroll
    for (int i = 0; i < 2; i++) {
      int chunk = i * 256 + tid;
      int row = chunk >> 3, c = chunk & 7;
      *(uint4v*)(sK + row * 72 + c * 8) =
          *(const uint4v*)(kbase + (size_t)(jt * 64 + row) * 64 + c * 8);
      *(uint4v*)(sV + row * 72 + c * 8) =
          *(const uint4v*)(vbase + (size_t)row * NPAD + jt * 64 + c * 8);
    }
    __syncthreads();

    // S = q . k  (2 x 16 rows x 64 j)
    float4v s[2][4];
#pragma unroll
    for (int ms = 0; ms < 2; ms++)
#pragma unroll
      for (int t = 0; t < 4; t++) s[ms][t] = (float4v)0.f;
#pragma unroll
    for (int ki = 0; ki < 2; ki++) {
#pragma unroll
      for (int t = 0; t < 4; t++) {
        short8 bk8 = *(const short8*)(sK + (t * 16 + ar) * 72 + ki * 32 + kq * 8);
#pragma unroll
        for (int ms = 0; ms < 2; ms++)
          s[ms][t] = __builtin_amdgcn_mfma_f32_16x16x32_bf16(aq[ms][ki], bk8, s[ms][t], 0, 0, 0);
      }
    }
    // mask j >= NTOK (only the last tile has any)
    if (jt == NJT - 1) {
#pragma unroll
      for (int t = 0; t < 4; t++)
        if ((NJT - 1) * 64 + t * 16 + ar >= NTOK) {
#pragma unroll
          for (int ms = 0; ms < 2; ms++) s[ms][t] = (float4v)(-INFINITY);
        }
    }
    // p = exp(s - SSHIFT); accumulate per-lane row partial sums; stage P
    asm volatile("" ::: "memory");
#pragma unroll
    for (int ms = 0; ms < 2; ms++)
#pragma unroll
      for (int t = 0; t < 4; t++)
#pragma unroll
        for (int r = 0; r < 4; r++) {
          float p = __expf(s[ms][t][r] - SSHIFT);
          rs[ms][r] += p;
          sP[(ms * 16 + kq * 4 + r) * 72 + t * 16 + ar] = f2bf(p);
        }
    asm volatile("" ::: "memory");  // LDS is per-wave in-order; just stop compiler reordering
#pragma unroll
    for (int ki = 0; ki < 2; ki++) {
#pragma unroll
      for (int ms = 0; ms < 2; ms++) {
        short8 ap = *(const short8*)(sP + (ms * 16 + ar) * 72 + ki * 32 + kq * 8);
#pragma unroll
        for (int t = 0; t < 4; t++) {
          short8 bv8 = *(const short8*)(sV + (t * 16 + ar) * 72 + ki * 32 + kq * 8);
          o_acc[ms][t] = __builtin_amdgcn_mfma_f32_16x16x32_bf16(ap, bv8, o_acc[ms][t], 0, 0, 0);
        }
      }
    }
  }
  // epilogue: one row-sum reduce, normalize, write attn_out bf16 for the O-GEMM
#pragma unroll
  for (int ms = 0; ms < 2; ms++)
#pragma unroll
    for (int r = 0; r < 4; r++) {
      float l = rs[ms][r];
#pragma unroll
      for (int off = 1; off < 16; off <<= 1) l += __shfl_xor(l, off, 64);
      int i = qt * 128 + wave * 32 + ms * 16 + kq * 4 + r;
      if (i >= NTOK) continue;
      float inv = 1.f / l;
      size_t mg = (size_t)b * NTOK + i;
#pragma unroll
      for (int t = 0; t < 4; t++)
        ao[mg * D + hh * 64 + t * 16 + ar] = f2bf(o_acc[ms][t][r] * inv);
    }
}

// ---------------- output projection ----------------
__global__ __launch_bounds__(512, 2) void gemm_o_kernel(const u16* __restrict__ A,
                                                        const u16* __restrict__ Wob,
                                                        const float* __restrict__ bo,
                                                        float* __restrict__ out) {
  __shared__ __align__(16) u16 As0[16384];
  __shared__ __align__(16) u16 Bs0[16384];
  __shared__ __align__(16) u16 As1[16384];
  __shared__ __align__(16) u16 Bs1[16384];
  const int ntile = blockIdx.x, mtile = blockIdx.y;
  float4v acc[8][4];
  gemm256_mainloop(A, Wob, As0, Bs0, As1, Bs1, mtile, ntile, acc);
  const int tid = threadIdx.x, lane = tid & 63, wave = tid >> 6;
  const int wm_idx = wave >> 2, wn_idx = wave & 3;
  const int ar = lane & 15, kq = lane >> 4;
  const int rowb = mtile * 256 + wm_idx * 128;
  const int colb = ntile * 256 + wn_idx * 64;
#pragma unroll
  for (int ms = 0; ms < 8; ms++) {
#pragma unroll
    for (int r = 0; r < 4; r++) {
      int grow = rowb + ms * 16 + kq * 4 + r;
      if (grow >= M_ROWS) continue;
#pragma unroll
      for (int ns = 0; ns < 4; ns++) {
        int col = colb + ns * 16 + ar;
        out[(size_t)grow * D + col] = acc[ms][ns][r] + bo[col];
      }
    }
  }
}

extern "C" void kernel_launch(void* const* d_in, const int* in_sizes, int n_in,
                              void* d_out, int out_size, void* d_ws, size_t ws_size,
                              hipStream_t stream) {
  const float* hidden = (const float*)d_in[0];
  const float* sinp = (const float*)d_in[1];
  const float* cosp = (const float*)d_in[2];
  const float* Wq = (const float*)d_in[3]; const float* bq = (const float*)d_in[4];
  const float* Wk = (const float*)d_in[5]; const float* bk = (const float*)d_in[6];
  const float* Wv = (const float*)d_in[7]; const float* bv = (const float*)d_in[8];
  const float* Wo = (const float*)d_in[9]; const float* bo = (const float*)d_in[10];
  float* out = (float*)d_out;
  (void)in_sizes; (void)n_in; (void)out_size; (void)ws_size;

  char* ws = (char*)d_ws;
  size_t off = 0;
  auto carve = [&](size_t elems) {
    u16* p = (u16*)(ws + off);
    off += ((elems * 2 + 255) & ~(size_t)255);
    return p;
  };
  u16* A_bf = carve((size_t)MPAD * KB);             // 34.1 MB (reused for attn_out)
  u16* Wqb = carve((size_t)D * KB);                 // 2.1 MB x4
  u16* Wkb = carve((size_t)D * KB);
  u16* Wvb = carve((size_t)D * KB);
  u16* Wob = carve((size_t)D * KB);
  u16* q_b = carve((size_t)BATCH * H * NPAD * 64);  // 37.7 MB x3   (total ~156 MB)
  u16* k_b = carve((size_t)BATCH * H * NPAD * 64);
  u16* v_t = carve((size_t)BATCH * H * NPAD * 64);

  hipLaunchKernelGGL(cvt_A_kernel, dim3(MPAD), dim3(256), 0, stream, hidden, A_bf);
  hipLaunchKernelGGL(cvt_W_kernel, dim3(1024, 4), dim3(256), 0, stream,
                     Wq, Wk, Wv, Wo, Wqb, Wkb, Wvb, Wob);
  hipLaunchKernelGGL(gemm_qkv_kernel, dim3(4, MT256, 3), dim3(512), 0, stream,
                     A_bf, Wqb, Wkb, Wvb, bq, bk, bv, sinp, cosp, q_b, k_b, v_t);
  hipLaunchKernelGGL(attn_kernel, dim3(9, H, BATCH), dim3(256), 0, stream, q_b, k_b, v_t, A_bf);
  hipLaunchKernelGGL(gemm_o_kernel, dim3(4, MT256), dim3(512), 0, stream, A_bf, Wob, bo, out);
}

// Round 5
// 628.961 us; speedup vs baseline: 1.1047x; 1.0422x over previous
//
#include <hip/hip_runtime.h>
#include <stdint.h>

#define H 16
#define HD 64
#define D 1024
#define NTOK 1029
#define BATCH 16
#define NPAD 1152           // 9*128 = 18*64
#define M_ROWS (BATCH*NTOK) // 16464
#define MPAD 16512          // 129*128
#define KB 1024
#define PREFIX 5

typedef unsigned short u16;
typedef __attribute__((ext_vector_type(8))) short short8;
typedef __attribute__((ext_vector_type(4))) short short4v;
typedef __attribute__((ext_vector_type(4))) float float4v;
typedef __attribute__((ext_vector_type(4))) unsigned int uint4v;

__device__ __forceinline__ u16 f2bf(float x) {
  unsigned int u = __float_as_uint(x);
  u += 0x7FFFu + ((u >> 16) & 1u);   // RNE
  return (u16)(u >> 16);
}

__device__ __forceinline__ void gload16(const void* g, void* l) {
  __builtin_amdgcn_global_load_lds((const __attribute__((address_space(1))) void*)g,
                                   (__attribute__((address_space(3))) void*)l, 16, 0, 0);
}

// ---------------- fp32 -> bf16 conversion ----------------
__global__ __launch_bounds__(256) void cvt_A_kernel(const float* __restrict__ src,
                                                    u16* __restrict__ dst) {
  int idx = blockIdx.x * 256 + threadIdx.x;  // MPAD*256 threads, 4 elems each
  int m = idx >> 8, k = (idx & 255) * 4;
  float4v x = (float4v)0.f;
  if (m < M_ROWS) x = *(const float4v*)(src + (size_t)m * D + k);
  short4v o;
#pragma unroll
  for (int j = 0; j < 4; j++) o[j] = (short)f2bf(x[j]);
  *(short4v*)(dst + (size_t)m * D + k) = o;
}

__global__ __launch_bounds__(256) void cvt_W_kernel(
    const float* __restrict__ w0, const float* __restrict__ w1,
    const float* __restrict__ w2, const float* __restrict__ w3,
    u16* __restrict__ e0, u16* __restrict__ e1, u16* __restrict__ e2, u16* __restrict__ e3) {
  const float* src = (blockIdx.y == 0) ? w0 : (blockIdx.y == 1) ? w1 : (blockIdx.y == 2) ? w2 : w3;
  u16* dst = (blockIdx.y == 0) ? e0 : (blockIdx.y == 1) ? e1 : (blockIdx.y == 2) ? e2 : e3;
  int idx = blockIdx.x * 256 + threadIdx.x;  // 1024*256 threads
  int m = idx >> 8, k = (idx & 255) * 4;
  float4v x = *(const float4v*)(src + (size_t)m * D + k);
  short4v o;
#pragma unroll
  for (int j = 0; j < 4; j++) o[j] = (short)f2bf(x[j]);
  *(short4v*)(dst + (size_t)m * D + k) = o;
}

// ---------------- 128x128 bf16 GEMM mainloop: BK=64, swizzled LDS ----------------
// m97 2-barrier structure (multi-block TLP hides drains), but:
//  - BK=64: half the barrier/drain events of BK=32, 2x MFMA per drain. 32 KiB LDS.
//  - XOR slot swizzle (verified rounds 1/3): 16B-slot within each 128B row ^= (row&7).
//    global_load_lds dest stays LINEAR (HW: base+lane*16); the SOURCE global address
//    carries the same involution; ds_read applies the XOR -> 2-way conflicts (free).
__device__ __forceinline__ void gemm_mainloop(const u16* __restrict__ A,
                                              const u16* __restrict__ Bw,
                                              u16* As, u16* Bs, int mtile, int ntile,
                                              float4v acc[4][4]) {
  const int tid = threadIdx.x;
  const int lane = tid & 63;
  const int wave = tid >> 6;
  const int wm = (wave >> 1) * 64;
  const int wn = (wave & 1) * 64;
  const int ar = lane & 15;
  const int kq = lane >> 4;
  // swizzled 16B-slot read offsets (u16 units) for k-slice 0/1: slot = ks*4+kq, ^ (ar&7)
  const int s0 = ((kq)     ^ (ar & 7)) * 8;
  const int s1 = ((4 + kq) ^ (ar & 7)) * 8;
  // staging: instr i covers rows i*32 + (tid>>3); source slot pre-swizzled
  const int srow = tid >> 3;                       // 0..31
  const int scol = ((tid & 7) ^ (srow & 7)) * 8;   // u16 units
  const int dswo = (tid & ~63) * 8;                // wave-uniform LDS dest base (u16)
  const u16* Ab = A + (size_t)mtile * 128 * KB + (size_t)srow * KB + scol;
  const u16* Bb = Bw + (size_t)ntile * 128 * KB + (size_t)srow * KB + scol;

#pragma unroll
  for (int i = 0; i < 4; i++)
#pragma unroll
    for (int j = 0; j < 4; j++) acc[i][j] = (float4v)0.f;

  for (int k0 = 0; k0 < KB; k0 += 64) {
    __syncthreads();
#pragma unroll
    for (int i = 0; i < 4; i++) {
      gload16(Ab + k0 + (size_t)i * 32 * KB, As + i * 2048 + dswo);
      gload16(Bb + k0 + (size_t)i * 32 * KB, Bs + i * 2048 + dswo);
    }
    __syncthreads();
#pragma unroll
    for (int ks = 0; ks < 2; ks++) {
      const int so = ks ? s1 : s0;
      short8 af[4], bf[4];
#pragma unroll
      for (int ms = 0; ms < 4; ms++)
        af[ms] = *(const short8*)(As + (wm + ms * 16 + ar) * 64 + so);
#pragma unroll
      for (int ns = 0; ns < 4; ns++)
        bf[ns] = *(const short8*)(Bs + (wn + ns * 16 + ar) * 64 + so);
#pragma unroll
      for (int ms = 0; ms < 4; ms++)
#pragma unroll
        for (int ns = 0; ns < 4; ns++)
          acc[ms][ns] = __builtin_amdgcn_mfma_f32_16x16x32_bf16(af[ms], bf[ns], acc[ms][ns], 0, 0, 0);
    }
  }
}

// ---------------- QKV projection + bias + RoPE ----------------
// q/k in [bh][n][64]; v transposed: vt[bh][d][n] (n padded to NPAD).
__global__ __launch_bounds__(256) void gemm_qkv_kernel(
    const u16* __restrict__ A,
    const u16* __restrict__ Wqb, const u16* __restrict__ Wkb, const u16* __restrict__ Wvb,
    const float* __restrict__ bq, const float* __restrict__ bk, const float* __restrict__ bv,
    const float* __restrict__ sinp, const float* __restrict__ cosp,
    u16* __restrict__ qb, u16* __restrict__ kb, u16* __restrict__ vt) {
  __shared__ __align__(16) u16 As[128 * 64];
  __shared__ __align__(16) u16 Bs[128 * 64];
  const int z = blockIdx.z;
  const u16* Bw = (z == 0) ? Wqb : (z == 1) ? Wkb : Wvb;
  const float* bias = (z == 0) ? bq : (z == 1) ? bk : bv;
  const int ntile = blockIdx.x, mtile = blockIdx.y;
  float4v acc[4][4];
  gemm_mainloop(A, Bw, As, Bs, mtile, ntile, acc);

  const int tid = threadIdx.x, lane = tid & 63, wave = tid >> 6;
  const int wm = (wave >> 1) * 64, wn = (wave & 1) * 64;
  const int ar = lane & 15, kq = lane >> 4;
#pragma unroll
  for (int ms = 0; ms < 4; ms++) {
#pragma unroll
    for (int r = 0; r < 4; r++) {
      int grow = mtile * 128 + wm + ms * 16 + kq * 4 + r;
      if (grow >= M_ROWS) continue;
      int b = grow / NTOK;
      int n = grow - b * NTOK;
      bool dorope = (z != 2) && (n >= PREFIX);
      int pos = n - PREFIX;
#pragma unroll
      for (int ns = 0; ns < 4; ns++) {
        int col = ntile * 128 + wn + ns * 16 + ar;
        int hh = col >> 6, d = col & 63;
        float y = acc[ms][ns][r] + bias[col];
        if (z == 2) {
          vt[((size_t)(b * H + hh) * 64 + d) * NPAD + n] = f2bf(y);
          continue;
        }
        if (dorope) {
          float xp = acc[ms][ns ^ 2][r] + bias[col ^ 32];  // partner d^32, same lane
          float c = cosp[pos * HD + d], s = sinp[pos * HD + d];
          y = y * c + ((d < 32) ? -xp : xp) * s;
        }
        if (z == 0) y *= 0.125f;  // fold 1/sqrt(HD) into q
        u16* outp = (z == 0) ? qb : kb;
        outp[((size_t)(b * H + hh) * NPAD + n) * 64 + d] = f2bf(y);
      }
    }
  }
}

// ---------------- flash attention: 128 q-rows/block, 4 waves x 32 rows ----------------
// Fixed-shift softmax (scores hard-bounded; shift cancels in normalization).
#define SSHIFT 3.0f
#define NJT 17   // ceil(NTOK/64): j-tiles 0..16; tile 16 masked, NO tile beyond
__global__ __launch_bounds__(256) void attn_kernel(const u16* __restrict__ qb,
                                                   const u16* __restrict__ kb,
                                                   const u16* __restrict__ vt,
                                                   u16* __restrict__ ao) {
  __shared__ __align__(16) u16 sQ[128 * 72];  // 18KB; per-wave sP (32x72) overlays own rows after preload
  __shared__ __align__(16) u16 sK[64 * 72];   // rows = j, cols = d
  __shared__ __align__(16) u16 sV[64 * 72];   // rows = d, cols = j (V^T staged directly)
  const int tid = threadIdx.x, lane = tid & 63, wave = tid >> 6;
  const int ar = lane & 15, kq = lane >> 4;
  const int qt = blockIdx.x, hh = blockIdx.y, b = blockIdx.z;
  const int bh = b * H + hh;
  const u16* qbase = qb + (size_t)bh * NPAD * 64;
  const u16* kbase = kb + (size_t)bh * NPAD * 64;
  const u16* vbase = vt + (size_t)bh * 64 * NPAD;

  // stage Q tile (128 x 64, stride 72)
#pragma unroll
  for (int i = 0; i < 4; i++) {
    int chunk = i * 256 + tid;
    int row = chunk >> 3, c = chunk & 7;
    *(uint4v*)(sQ + row * 72 + c * 8) =
        *(const uint4v*)(qbase + (size_t)(qt * 128 + row) * 64 + c * 8);
  }
  __syncthreads();
  short8 aq[2][2];  // this wave's q A-frags (rows wave*32 + ms*16 + ar)
#pragma unroll
  for (int ms = 0; ms < 2; ms++)
#pragma unroll
    for (int ki = 0; ki < 2; ki++)
      aq[ms][ki] = *(const short8*)(sQ + (wave * 32 + ms * 16 + ar) * 72 + ki * 32 + kq * 8);
  u16* sP = sQ + wave * 32 * 72;  // wave-private P tile (32 x 64) over this wave's own sQ rows

  float rs[2][4];
  float4v o_acc[2][4];
#pragma unroll
  for (int ms = 0; ms < 2; ms++)
#pragma unroll
    for (int r = 0; r < 4; r++) rs[ms][r] = 0.f;
#pragma unroll
  for (int ms = 0; ms < 2; ms++)
#pragma unroll
    for (int t = 0; t < 4; t++) o_acc[ms][t] = (float4v)0.f;

  for (int jt = 0; jt < NJT; jt++) {
    __syncthreads();  // prev-iteration sK/sV frag reads complete
#pragma unroll
    for (int i = 0; i < 2; i++) {
      int chunk = i * 256 + tid;
      int row = chunk >> 3, c = chunk & 7;
      *(uint4v*)(sK + row * 72 + c * 8) =
          *(const uint4v*)(kbase + (size_t)(jt * 64 + row) * 64 + c * 8);
      *(uint4v*)(sV + row * 72 + c * 8) =
          *(const uint4v*)(vbase + (size_t)row * NPAD + jt * 64 + c * 8);
    }
    __syncthreads();

    // S = q . k  (2 x 16 rows x 64 j)
    float4v s[2][4];
#pragma unroll
    for (int ms = 0; ms < 2; ms++)
#pragma unroll
      for (int t = 0; t < 4; t++) s[ms][t] = (float4v)0.f;
#pragma unroll
    for (int ki = 0; ki < 2; ki++) {
#pragma unroll
      for (int t = 0; t < 4; t++) {
        short8 bk8 = *(const short8*)(sK + (t * 16 + ar) * 72 + ki * 32 + kq * 8);
#pragma unroll
        for (int ms = 0; ms < 2; ms++)
          s[ms][t] = __builtin_amdgcn_mfma_f32_16x16x32_bf16(aq[ms][ki], bk8, s[ms][t], 0, 0, 0);
      }
    }
    // mask j >= NTOK (only the last tile has any)
    if (jt == NJT - 1) {
#pragma unroll
      for (int t = 0; t < 4; t++)
        if ((NJT - 1) * 64 + t * 16 + ar >= NTOK) {
#pragma unroll
          for (int ms = 0; ms < 2; ms++) s[ms][t] = (float4v)(-INFINITY);
        }
    }
    // p = exp(s - SSHIFT); accumulate per-lane row partial sums; stage P
    asm volatile("" ::: "memory");
#pragma unroll
    for (int ms = 0; ms < 2; ms++)
#pragma unroll
      for (int t = 0; t < 4; t++)
#pragma unroll
        for (int r = 0; r < 4; r++) {
          float p = __expf(s[ms][t][r] - SSHIFT);
          rs[ms][r] += p;
          sP[(ms * 16 + kq * 4 + r) * 72 + t * 16 + ar] = f2bf(p);
        }
    asm volatile("" ::: "memory");  // LDS is per-wave in-order; just stop compiler reordering
#pragma unroll
    for (int ki = 0; ki < 2; ki++) {
#pragma unroll
      for (int ms = 0; ms < 2; ms++) {
        short8 ap = *(const short8*)(sP + (ms * 16 + ar) * 72 + ki * 32 + kq * 8);
#pragma unroll
        for (int t = 0; t < 4; t++) {
          short8 bv8 = *(const short8*)(sV + (t * 16 + ar) * 72 + ki * 32 + kq * 8);
          o_acc[ms][t] = __builtin_amdgcn_mfma_f32_16x16x32_bf16(ap, bv8, o_acc[ms][t], 0, 0, 0);
        }
      }
    }
  }
  // epilogue: one row-sum reduce, normalize, write attn_out bf16 for the O-GEMM
#pragma unroll
  for (int ms = 0; ms < 2; ms++)
#pragma unroll
    for (int r = 0; r < 4; r++) {
      float l = rs[ms][r];
#pragma unroll
      for (int off = 1; off < 16; off <<= 1) l += __shfl_xor(l, off, 64);
      int i = qt * 128 + wave * 32 + ms * 16 + kq * 4 + r;
      if (i >= NTOK) continue;
      float inv = 1.f / l;
      size_t mg = (size_t)b * NTOK + i;
#pragma unroll
      for (int t = 0; t < 4; t++)
        ao[mg * D + hh * 64 + t * 16 + ar] = f2bf(o_acc[ms][t][r] * inv);
    }
}

// ---------------- output projection ----------------
__global__ __launch_bounds__(256) void gemm_o_kernel(const u16* __restrict__ A,
                                                     const u16* __restrict__ Wob,
                                                     const float* __restrict__ bo,
                                                     float* __restrict__ out) {
  __shared__ __align__(16) u16 As[128 * 64];
  __shared__ __align__(16) u16 Bs[128 * 64];
  const int ntile = blockIdx.x, mtile = blockIdx.y;
  float4v acc[4][4];
  gemm_mainloop(A, Wob, As, Bs, mtile, ntile, acc);
  const int tid = threadIdx.x, lane = tid & 63, wave = tid >> 6;
  const int wm = (wave >> 1) * 64, wn = (wave & 1) * 64;
  const int ar = lane & 15, kq = lane >> 4;
#pragma unroll
  for (int ms = 0; ms < 4; ms++)
#pragma unroll
    for (int r = 0; r < 4; r++) {
      int grow = mtile * 128 + wm + ms * 16 + kq * 4 + r;
      if (grow >= M_ROWS) continue;
#pragma unroll
      for (int ns = 0; ns < 4; ns++) {
        int col = ntile * 128 + wn + ns * 16 + ar;
        out[(size_t)grow * D + col] = acc[ms][ns][r] + bo[col];
      }
    }
}

extern "C" void kernel_launch(void* const* d_in, const int* in_sizes, int n_in,
                              void* d_out, int out_size, void* d_ws, size_t ws_size,
                              hipStream_t stream) {
  const float* hidden = (const float*)d_in[0];
  const float* sinp = (const float*)d_in[1];
  const float* cosp = (const float*)d_in[2];
  const float* Wq = (const float*)d_in[3]; const float* bq = (const float*)d_in[4];
  const float* Wk = (const float*)d_in[5]; const float* bk = (const float*)d_in[6];
  const float* Wv = (const float*)d_in[7]; const float* bv = (const float*)d_in[8];
  const float* Wo = (const float*)d_in[9]; const float* bo = (const float*)d_in[10];
  float* out = (float*)d_out;
  (void)in_sizes; (void)n_in; (void)out_size; (void)ws_size;

  char* ws = (char*)d_ws;
  size_t off = 0;
  auto carve = [&](size_t elems) {
    u16* p = (u16*)(ws + off);
    off += ((elems * 2 + 255) & ~(size_t)255);
    return p;
  };
  u16* A_bf = carve((size_t)MPAD * KB);             // 33.8 MB (reused for attn_out)
  u16* Wqb = carve((size_t)D * KB);                 // 2.1 MB x4
  u16* Wkb = carve((size_t)D * KB);
  u16* Wvb = carve((size_t)D * KB);
  u16* Wob = carve((size_t)D * KB);
  u16* q_b = carve((size_t)BATCH * H * NPAD * 64);  // 37.7 MB x3   (total ~155 MB)
  u16* k_b = carve((size_t)BATCH * H * NPAD * 64);
  u16* v_t = carve((size_t)BATCH * H * NPAD * 64);

  hipLaunchKernelGGL(cvt_A_kernel, dim3(MPAD), dim3(256), 0, stream, hidden, A_bf);
  hipLaunchKernelGGL(cvt_W_kernel, dim3(1024, 4), dim3(256), 0, stream,
                     Wq, Wk, Wv, Wo, Wqb, Wkb, Wvb, Wob);
  hipLaunchKernelGGL(gemm_qkv_kernel, dim3(8, 129, 3), dim3(256), 0, stream,
                     A_bf, Wqb, Wkb, Wvb, bq, bk, bv, sinp, cosp, q_b, k_b, v_t);
  hipLaunchKernelGGL(attn_kernel, dim3(9, H, BATCH), dim3(256), 0, stream, q_b, k_b, v_t, A_bf);
  hipLaunchKernelGGL(gemm_o_kernel, dim3(8, 129), dim3(256), 0, stream, A_bf, Wob, bo, out);
}